// Round 18
// baseline (3807.623 us; speedup 1.0000x reference)
//
#include <hip/hip_runtime.h>
#include <hip/hip_bf16.h>

typedef __attribute__((ext_vector_type(8))) short short8;
typedef __attribute__((ext_vector_type(4))) short short4v;
typedef __attribute__((ext_vector_type(4))) float f32x4;
typedef __attribute__((ext_vector_type(16))) float f32x16;
typedef __attribute__((address_space(3))) char lds_char;

static __device__ __forceinline__ ushort f2bf(float f) {
  union { __hip_bfloat16 h; ushort u; } cv;
  cv.h = __float2bfloat16(f);
  return cv.u;
}

#define GLOAD_LDS16(gp, lp)                                            \
  __builtin_amdgcn_global_load_lds(                                    \
      (const __attribute__((address_space(1))) void*)(gp),             \
      (__attribute__((address_space(3))) void*)(lp), 16, 0, 0)

#define BAR   asm volatile("s_barrier" ::: "memory")
#define VM0   asm volatile("s_waitcnt vmcnt(0)" ::: "memory")
// attn tr_read path: inline-asm ds_read -> rule #18 (fence required).
#define LGKM0_SB do { asm volatile("s_waitcnt lgkmcnt(0)" ::: "memory");  \
                      __builtin_amdgcn_sched_barrier(0); } while (0)

// ---------------- fused fp32 -> bf16 convert for all 4 weight tensors ----------------
__global__ __launch_bounds__(256) void cvt_all_k(const float* __restrict__ w0, ushort* __restrict__ o0, int n0,
                                                 const float* __restrict__ w1, ushort* __restrict__ o1, int n1,
                                                 const float* __restrict__ w2, ushort* __restrict__ o2, int n2,
                                                 const float* __restrict__ w3, ushort* __restrict__ o3, int n3) {
  int i = blockIdx.x * 256 + threadIdx.x;
  const float* in; ushort* out;
  if (i < n0)           { in = w0; out = o0; }
  else if (i < n0 + n1) { i -= n0; in = w1; out = o1; }
  else if (i < n0 + n1 + n2) { i -= n0 + n1; in = w2; out = o2; }
  else                  { i -= n0 + n1 + n2; if (i >= n3) return; in = w3; out = o3; }
  const float4* p = (const float4*)in + (size_t)i * 2;
  float4 a = p[0], b = p[1];
  short8 o;
  o[0] = f2bf(a.x); o[1] = f2bf(a.y); o[2] = f2bf(a.z); o[3] = f2bf(a.w);
  o[4] = f2bf(b.x); o[5] = f2bf(b.y); o[6] = f2bf(b.z); o[7] = f2bf(b.w);
  ((short8*)out)[i] = o;
}

// ---------------- LayerNorm fp32 -> bf16 (C=2048, one row per block) ----------------
__global__ __launch_bounds__(256) void ln_k(const float* __restrict__ x, const float* __restrict__ w,
                                            const float* __restrict__ b, ushort* __restrict__ o) {
  const int row = blockIdx.x, t = threadIdx.x;
  const float* xr = x + (size_t)row * 2048;
  float4 v0 = *(const float4*)(xr + t * 4);
  float4 v1 = *(const float4*)(xr + t * 4 + 1024);
  float s  = v0.x + v0.y + v0.z + v0.w + v1.x + v1.y + v1.z + v1.w;
  float s2 = v0.x*v0.x + v0.y*v0.y + v0.z*v0.z + v0.w*v0.w
           + v1.x*v1.x + v1.y*v1.y + v1.z*v1.z + v1.w*v1.w;
  #pragma unroll
  for (int m = 32; m; m >>= 1) { s += __shfl_xor(s, m); s2 += __shfl_xor(s2, m); }
  __shared__ float red[8];
  const int lane = t & 63, wv = t >> 6;
  if (lane == 0) { red[wv * 2] = s; red[wv * 2 + 1] = s2; }
  __syncthreads();
  s  = red[0] + red[2] + red[4] + red[6];
  s2 = red[1] + red[3] + red[5] + red[7];
  const float mu = s * (1.f / 2048.f);
  const float rstd = rsqrtf(s2 * (1.f / 2048.f) - mu * mu + 1e-5f);
  float4 w0 = *(const float4*)(w + t * 4), w1 = *(const float4*)(w + t * 4 + 1024);
  float4 b0 = *(const float4*)(b + t * 4), b1 = *(const float4*)(b + t * 4 + 1024);
  short4v o0, o1;
  o0[0] = f2bf((v0.x - mu) * rstd * w0.x + b0.x);
  o0[1] = f2bf((v0.y - mu) * rstd * w0.y + b0.y);
  o0[2] = f2bf((v0.z - mu) * rstd * w0.z + b0.z);
  o0[3] = f2bf((v0.w - mu) * rstd * w0.w + b0.w);
  o1[0] = f2bf((v1.x - mu) * rstd * w1.x + b1.x);
  o1[1] = f2bf((v1.y - mu) * rstd * w1.y + b1.y);
  o1[2] = f2bf((v1.z - mu) * rstd * w1.z + b1.z);
  o1[3] = f2bf((v1.w - mu) * rstd * w1.w + b1.w);
  *(short4v*)(o + (size_t)row * 2048 + t * 4) = o0;
  *(short4v*)(o + (size_t)row * 2048 + t * 4 + 1024) = o1;
}

// ---------------- 256x128 bf16 GEMM, 32x32x16 MFMA, 3 blocks/CU ----------------
// R17: 4 waves (2M x 2N), per-wave 128x64 = 4x2 tiles of 32x32; acc 128 AGPR.
// 32x32x16 halves LDS-read bytes per FLOP vs 16x16x32 (same 8-bf16 frags, 2x
// FLOP/MFMA) -> per block-K-tile LDS 96 instr (~1152cy) ~ MFMA 128 instr
// (~1033cy): balanced. LDS 48KB -> 3 blocks/CU interleave the full-drain sync:
//   VM0; BAR; setprio(1){ per-ks: 6 reads + 8 MFMA }setprio(0); BAR; stage(t+1)
// Fragment layouts: A lane l -> row=l&31, k=(l>>5)*8+j ; B symmetric (W-row
// l&31, k-octet l>>5). C/D (m74/m101): col=lane&31, row=(reg&3)+8*(reg>>2)+4*(lane>>5).
// Swizzle XOR = (r32&7)<<4 (row&7 invariant across m*32 / wr*128 offsets).
template <int EPI>
__global__ __launch_bounds__(256, 3) void gemm32_k(const ushort* __restrict__ A, const ushort* __restrict__ B,
                                                   const float* __restrict__ bias, const float* __restrict__ res,
                                                   void* __restrict__ outp, int M, int N, int K) {
  __shared__ __align__(16) char lds[49152];  // A 256x64 @0 (32KB), B 128x64 @32768 (16KB)
  const int nbn = N >> 7;
  const int nwg = gridDim.x;
  const int cpx = nwg >> 3;
  const int bid = (blockIdx.x & 7) * cpx + (blockIdx.x >> 3);
  const int gsz = nbn << 2;
  const int g = bid / gsz, rr = bid % gsz;
  const int bm = (g << 2) + (rr & 3), bn = rr >> 2;
  const int m0 = bm << 8, n0 = bn << 7;
  const int t = threadIdx.x, lane = t & 63, wid = t >> 6;
  const int wr = wid >> 1, wc = wid & 1;
  const int r32 = lane & 31, kg = lane >> 5;
  const int srow = lane >> 3, sc8 = lane & 7;
  const int gcs = (sc8 ^ srow) * 8;  // pre-swizzled global column (elements)
  const ushort* Abase = A + (size_t)m0 * K;
  const ushort* Bbase = B + (size_t)n0 * K;
  f32x16 acc[4][2] = {};

  auto stageA = [&](int tt) {
    const size_t kof = (size_t)tt * 64 + gcs;
    #pragma unroll
    for (int j = 0; j < 8; j++) {
      const int rb = wid * 64 + j * 8;
      GLOAD_LDS16(Abase + (size_t)(rb + srow) * K + kof, (ushort*)(lds + rb * 128));
    }
  };
  auto stageB = [&](int tt) {
    const size_t kof = (size_t)tt * 64 + gcs;
    #pragma unroll
    for (int j = 0; j < 4; j++) {
      const int rb = wid * 32 + j * 8;
      GLOAD_LDS16(Bbase + (size_t)(rb + srow) * K + kof, (ushort*)(lds + 32768 + rb * 128));
    }
  };

  const int swz = (r32 & 7) << 4;
  const char* LA = lds + (wr * 128 + r32) * 128;           // + m*4096 + colbyte
  const char* LB = lds + 32768 + (wc * 64 + r32) * 128;    // + n*4096 + colbyte
  const int kcol0 = kg * 16;  // byte offset of this lane's k-octet

  const int NT = K >> 6;
  stageA(0); stageB(0);

  for (int tt = 0; tt < NT; ++tt) {
    VM0; BAR;  // tile tt fully staged & visible
    __builtin_amdgcn_s_setprio(1);
    #pragma unroll
    for (int ks = 0; ks < 4; ks++) {
      const int cb = (ks * 32 + kcol0) ^ swz;
      short8 bf0 = *(const short8*)(LB + cb);
      short8 bf1 = *(const short8*)(LB + 4096 + cb);
      #pragma unroll
      for (int m = 0; m < 4; m++) {
        short8 af = *(const short8*)(LA + m * 4096 + cb);
        acc[m][0] = __builtin_amdgcn_mfma_f32_32x32x16_bf16(af, bf0, acc[m][0], 0, 0, 0);
        acc[m][1] = __builtin_amdgcn_mfma_f32_32x32x16_bf16(af, bf1, acc[m][1], 0, 0, 0);
      }
    }
    __builtin_amdgcn_s_setprio(0);
    BAR;  // all reads consumed -> buffer free for next stage
    if (tt + 1 < NT) { stageA(tt + 1); stageB(tt + 1); }
  }

  #pragma unroll
  for (int m = 0; m < 4; m++) {
    const int gm = m0 + wr * 128 + m * 32 + 4 * kg;
    #pragma unroll
    for (int n = 0; n < 2; n++) {
      const int gcol = n0 + wc * 64 + n * 32 + r32;
      const float bv = bias[gcol];
      #pragma unroll
      for (int r = 0; r < 16; r++) {
        const int grow = gm + (r & 3) + 8 * (r >> 2);
        const size_t idx = (size_t)grow * N + gcol;
        float v = acc[m][n][r] + bv;
        if constexpr (EPI == 0) ((ushort*)outp)[idx] = f2bf(v);
        else if constexpr (EPI == 1) ((float*)outp)[idx] = res[idx] + v;
        else if constexpr (EPI == 2) ((ushort*)outp)[idx] = f2bf(0.5f * v * (1.f + erff(v * 0.70710678118f)));
        else ((float*)outp)[idx] += v;
      }
    }
  }
}

// ---------------- causal flash attention (verified R5 structure) ----------------
__global__ __launch_bounds__(256) void attn_k(const ushort* __restrict__ qkv, ushort* __restrict__ o) {
  const int qb = 15 - blockIdx.y;
  const int bh = blockIdx.x;
  const int bb = bh >> 4, h = bh & 15;
  const int t = threadIdx.x, lane = t & 63, w = t >> 6;
  const int hi = lane >> 4, lo = lane & 15;
  __shared__ __align__(16) char ldsK[64 * 256];
  __shared__ __align__(16) char ldsV[64 * 256];
  __shared__ __align__(16) char ldsP[4][16 * 128];
  const size_t base = (size_t)bb * 1024 * 6144;
  const int qrow_a = qb * 64 + w * 16 + lo;
  short8 qf[4];
  #pragma unroll
  for (int kk = 0; kk < 4; kk++)
    qf[kk] = *(const short8*)(qkv + base + (size_t)qrow_a * 6144 + h * 128 + kk * 32 + hi * 8);
  float ms[4], ls[4];
  f32x4 oacc[8] = {};
  #pragma unroll
  for (int r = 0; r < 4; r++) { ms[r] = -1e30f; ls[r] = 0.f; }
  const int wave_qmax = qb * 64 + w * 16 + 15;
  const uint vbase = (uint)(size_t)(lds_char*)ldsV + hi * 2048 + lo * 8;
  const int k_r4  = lane >> 4;
  const int v_kv4 = (lane >> 1) & 3;
  const int v_d0  = (lane >> 3) * 16 + (lane & 1) * 8;

  for (int kv0 = 0; kv0 <= qb * 64; kv0 += 64) {
    __syncthreads();
    #pragma unroll
    for (int j = 0; j < 4; j++) {
      const int rb = w * 16 + j * 4;
      const int r  = rb + k_r4;
      const int c16 = (lane & 15) ^ (r & 7);
      GLOAD_LDS16(qkv + base + (size_t)(kv0 + r) * 6144 + 2048 + h * 128 + c16 * 8,
                  ldsK + rb * 256);
    }
    #pragma unroll
    for (int j = 0; j < 4; j++) {
      const int g = w * 4 + j;
      GLOAD_LDS16(qkv + base + (size_t)(kv0 + g * 4 + v_kv4) * 6144 + 4096 + h * 128 + v_d0,
                  ldsV + g * 1024);
    }
    __syncthreads();
    if (kv0 > wave_qmax) continue;
    f32x4 s[4];
    #pragma unroll
    for (int nb = 0; nb < 4; nb++) {
      f32x4 z = {};
      const int krow = nb * 16 + lo;
      #pragma unroll
      for (int kk = 0; kk < 4; kk++) {
        const int cb = kk * 64 + hi * 16;
        short8 kf = *(const short8*)(ldsK + krow * 256 + (cb ^ ((krow & 7) << 4)));
        z = __builtin_amdgcn_mfma_f32_16x16x32_bf16(qf[kk], kf, z, 0, 0, 0);
      }
      s[nb] = z;
    }
    float corr[4];
    #pragma unroll
    for (int r = 0; r < 4; r++) {
      const int qrow = qb * 64 + w * 16 + hi * 4 + r;
      float mx = -1e30f;
      #pragma unroll
      for (int nb = 0; nb < 4; nb++) {
        const int kcol = kv0 + nb * 16 + lo;
        float sv = s[nb][r] * 0.08838834764831845f;
        sv = (kcol <= qrow) ? sv : -1e30f;
        s[nb][r] = sv;
        mx = fmaxf(mx, sv);
      }
      #pragma unroll
      for (int msk = 1; msk < 16; msk <<= 1) mx = fmaxf(mx, __shfl_xor(mx, msk));
      const float mnew = fmaxf(ms[r], mx);
      corr[r] = __expf(ms[r] - mnew);
      ms[r] = mnew;
      float rs = 0.f;
      #pragma unroll
      for (int nb = 0; nb < 4; nb++) {
        const float p = __expf(s[nb][r] - mnew);
        s[nb][r] = p; rs += p;
      }
      #pragma unroll
      for (int msk = 1; msk < 16; msk <<= 1) rs += __shfl_xor(rs, msk);
      ls[r] = ls[r] * corr[r] + rs;
    }
    #pragma unroll
    for (int nf = 0; nf < 8; nf++)
      #pragma unroll
      for (int r = 0; r < 4; r++) oacc[nf][r] *= corr[r];
    #pragma unroll
    for (int r = 0; r < 4; r++) {
      const int prow = hi * 4 + r;
      #pragma unroll
      for (int nb = 0; nb < 4; nb++) {
        const int pcol = nb * 16 + lo;
        *(short*)(ldsP[w] + prow * 128 + ((pcol * 2) ^ ((prow & 7) << 4))) = (short)f2bf(s[nb][r]);
      }
    }
    #pragma unroll
    for (int ks = 0; ks < 2; ks++) {
      short8 pf = *(const short8*)(ldsP[w] + lo * 128 + ((ks * 64 + hi * 16) ^ ((lo & 7) << 4)));
      short4v v0[8], v1[8];
      #pragma unroll
      for (int nf = 0; nf < 8; nf++) {
        const uint a0 = vbase + ks * 8192 + nf * 128;
        asm volatile("ds_read_b64_tr_b16 %0, %1" : "=v"(v0[nf]) : "v"(a0));
        asm volatile("ds_read_b64_tr_b16 %0, %1" : "=v"(v1[nf]) : "v"(a0 + 1024));
      }
      LGKM0_SB;
      #pragma unroll
      for (int nf = 0; nf < 8; nf++) {
        short8 vf = __builtin_shufflevector(v0[nf], v1[nf], 0, 1, 2, 3, 4, 5, 6, 7);
        oacc[nf] = __builtin_amdgcn_mfma_f32_16x16x32_bf16(pf, vf, oacc[nf], 0, 0, 0);
      }
    }
  }
  #pragma unroll
  for (int r = 0; r < 4; r++) {
    const float inv = 1.f / ls[r];
    const int qrow = qb * 64 + w * 16 + hi * 4 + r;
    ushort* orow = o + ((size_t)(bb * 1024 + qrow)) * 2048 + h * 128;
    #pragma unroll
    for (int nf = 0; nf < 8; nf++)
      orow[nf * 16 + lo] = f2bf(oacc[nf][r] * inv);
  }
}

extern "C" void kernel_launch(void* const* d_in, const int* in_sizes, int n_in,
                              void* d_out, int out_size, void* d_ws, size_t ws_size,
                              hipStream_t stream) {
  const float* x     = (const float*)d_in[0];
  const float* ln1w  = (const float*)d_in[1];
  const float* ln1b  = (const float*)d_in[2];
  const float* qkvw  = (const float*)d_in[3];
  const float* qkvb  = (const float*)d_in[4];
  const float* outw  = (const float*)d_in[5];
  const float* outb  = (const float*)d_in[6];
  const float* ln2w  = (const float*)d_in[7];
  const float* ln2b  = (const float*)d_in[8];
  const float* fc1w  = (const float*)d_in[9];
  const float* fc1b  = (const float*)d_in[10];
  const float* fc2w  = (const float*)d_in[11];
  const float* fc2b  = (const float*)d_in[12];
  float* out = (float*)d_out;

  char* ws = (char*)d_ws;
  ushort* qkvw_bf = (ushort*)(ws);               // 3*2048*2048 bf16
  ushort* outw_bf = (ushort*)(ws + 25165824);    // 2048*2048
  ushort* fc1w_bf = (ushort*)(ws + 33554432);    // 8192*2048
  ushort* fc2w_bf = (ushort*)(ws + 67108864);    // 2048*8192
  ushort* bufA    = (ushort*)(ws + 100663296);   // 8192*2048 bf16
  ushort* bufR    = (ushort*)(ws + 134217728);   // 8192*8192 bf16 max

  cvt_all_k<<<24576, 256, 0, stream>>>(qkvw, qkvw_bf, 1572864,
                                       outw, outw_bf, 524288,
                                       fc1w, fc1w_bf, 2097152,
                                       fc2w, fc2w_bf, 2097152);

  ln_k<<<8192, 256, 0, stream>>>(x, ln1w, ln1b, bufA);
  // QKV: 32 x 48 = 1536 blocks
  gemm32_k<0><<<1536, 256, 0, stream>>>(bufA, qkvw_bf, qkvb, nullptr, bufR, 8192, 6144, 2048);
  attn_k<<<dim3(128, 16), 256, 0, stream>>>(bufR, bufA);
  // out-proj: 32 x 16 = 512 blocks
  gemm32_k<1><<<512, 256, 0, stream>>>(bufA, outw_bf, outb, x, out, 8192, 2048, 2048);
  ln_k<<<8192, 256, 0, stream>>>(out, ln2w, ln2b, bufA);
  // FC1: 32 x 64 = 2048 blocks
  gemm32_k<2><<<2048, 256, 0, stream>>>(bufA, fc1w_bf, fc1b, nullptr, bufR, 8192, 8192, 2048);
  // FC2: 32 x 16 = 512 blocks
  gemm32_k<3><<<512, 256, 0, stream>>>(bufR, fc2w_bf, fc2b, nullptr, out, 8192, 2048, 8192);
}

// Round 19
// 958.977 us; speedup vs baseline: 3.9705x; 3.9705x over previous
//
#include <hip/hip_runtime.h>
#include <hip/hip_bf16.h>

typedef __attribute__((ext_vector_type(8))) short short8;
typedef __attribute__((ext_vector_type(4))) short short4v;
typedef __attribute__((ext_vector_type(4))) float f32x4;
typedef __attribute__((address_space(3))) char lds_char;

static __device__ __forceinline__ ushort f2bf(float f) {
  union { __hip_bfloat16 h; ushort u; } cv;
  cv.h = __float2bfloat16(f);
  return cv.u;
}

#define GLOAD_LDS16(gp, lp)                                            \
  __builtin_amdgcn_global_load_lds(                                    \
      (const __attribute__((address_space(1))) void*)(gp),             \
      (__attribute__((address_space(3))) void*)(lp), 16, 0, 0)

#define BAR   asm volatile("s_barrier" ::: "memory")
#define VM0   asm volatile("s_waitcnt vmcnt(0)" ::: "memory")
#define VM6   asm volatile("s_waitcnt vmcnt(6)" ::: "memory")
// attn tr_read path: inline-asm ds_read -> rule #18 (fence required).
#define LGKM0_SB do { asm volatile("s_waitcnt lgkmcnt(0)" ::: "memory");  \
                      __builtin_amdgcn_sched_barrier(0); } while (0)

// ---------------- fused fp32 -> bf16 convert for all 4 weight tensors ----------------
__global__ __launch_bounds__(256) void cvt_all_k(const float* __restrict__ w0, ushort* __restrict__ o0, int n0,
                                                 const float* __restrict__ w1, ushort* __restrict__ o1, int n1,
                                                 const float* __restrict__ w2, ushort* __restrict__ o2, int n2,
                                                 const float* __restrict__ w3, ushort* __restrict__ o3, int n3) {
  int i = blockIdx.x * 256 + threadIdx.x;
  const float* in; ushort* out;
  if (i < n0)           { in = w0; out = o0; }
  else if (i < n0 + n1) { i -= n0; in = w1; out = o1; }
  else if (i < n0 + n1 + n2) { i -= n0 + n1; in = w2; out = o2; }
  else                  { i -= n0 + n1 + n2; if (i >= n3) return; in = w3; out = o3; }
  const float4* p = (const float4*)in + (size_t)i * 2;
  float4 a = p[0], b = p[1];
  short8 o;
  o[0] = f2bf(a.x); o[1] = f2bf(a.y); o[2] = f2bf(a.z); o[3] = f2bf(a.w);
  o[4] = f2bf(b.x); o[5] = f2bf(b.y); o[6] = f2bf(b.z); o[7] = f2bf(b.w);
  ((short8*)out)[i] = o;
}

// ---------------- LayerNorm fp32 -> bf16 (C=2048, one row per block) ----------------
__global__ __launch_bounds__(256) void ln_k(const float* __restrict__ x, const float* __restrict__ w,
                                            const float* __restrict__ b, ushort* __restrict__ o) {
  const int row = blockIdx.x, t = threadIdx.x;
  const float* xr = x + (size_t)row * 2048;
  float4 v0 = *(const float4*)(xr + t * 4);
  float4 v1 = *(const float4*)(xr + t * 4 + 1024);
  float s  = v0.x + v0.y + v0.z + v0.w + v1.x + v1.y + v1.z + v1.w;
  float s2 = v0.x*v0.x + v0.y*v0.y + v0.z*v0.z + v0.w*v0.w
           + v1.x*v1.x + v1.y*v1.y + v1.z*v1.z + v1.w*v1.w;
  #pragma unroll
  for (int m = 32; m; m >>= 1) { s += __shfl_xor(s, m); s2 += __shfl_xor(s2, m); }
  __shared__ float red[8];
  const int lane = t & 63, wv = t >> 6;
  if (lane == 0) { red[wv * 2] = s; red[wv * 2 + 1] = s2; }
  __syncthreads();
  s  = red[0] + red[2] + red[4] + red[6];
  s2 = red[1] + red[3] + red[5] + red[7];
  const float mu = s * (1.f / 2048.f);
  const float rstd = rsqrtf(s2 * (1.f / 2048.f) - mu * mu + 1e-5f);
  float4 w0 = *(const float4*)(w + t * 4), w1 = *(const float4*)(w + t * 4 + 1024);
  float4 b0 = *(const float4*)(b + t * 4), b1 = *(const float4*)(b + t * 4 + 1024);
  short4v o0, o1;
  o0[0] = f2bf((v0.x - mu) * rstd * w0.x + b0.x);
  o0[1] = f2bf((v0.y - mu) * rstd * w0.y + b0.y);
  o0[2] = f2bf((v0.z - mu) * rstd * w0.z + b0.z);
  o0[3] = f2bf((v0.w - mu) * rstd * w0.w + b0.w);
  o1[0] = f2bf((v1.x - mu) * rstd * w1.x + b1.x);
  o1[1] = f2bf((v1.y - mu) * rstd * w1.y + b1.y);
  o1[2] = f2bf((v1.z - mu) * rstd * w1.z + b1.z);
  o1[3] = f2bf((v1.w - mu) * rstd * w1.w + b1.w);
  *(short4v*)(o + (size_t)row * 2048 + t * 4) = o0;
  *(short4v*)(o + (size_t)row * 2048 + t * 4 + 1024) = o1;
}

// ---------------- 256x256 8-phase bf16 GEMM, single-barrier phases (verified best) ----------------
// R11/R15 schedule (fc1-class 303us, MfmaUtil 41%):
//   phase = { ds_reads(cur quadrant) ; stage ; s_barrier ; setprio(1) MFMA setprio(0) }
// Stage slots: ph0 A1(v)->buf1 ; ph2 A0+B0, ph3 B1, ph4 A1 (u+2)->buf0 ;
//              ph6 A0+B0, ph7 B1 (u+3)->buf1. VM6 at ph3/ph7; lastI VM0@ph3.
// setprio A/B-verified +10% on this structure (R14: 303 vs 336 us).
template <int EPI>
__global__ __launch_bounds__(512) void gemm256_k(const ushort* __restrict__ A, const ushort* __restrict__ B,
                                                 const float* __restrict__ bias, const float* __restrict__ res,
                                                 void* __restrict__ outp, int M, int N, int K) {
  __shared__ __align__(16) char lds[2][65536];
  const int nbn = N >> 8;
  const int nwg = gridDim.x;
  const int cpx = nwg >> 3;
  const int bid = (blockIdx.x & 7) * cpx + (blockIdx.x >> 3);
  const int gsz = nbn << 2;
  const int g = bid / gsz, rr = bid % gsz;
  const int bm = (g << 2) + (rr & 3), bn = rr >> 2;
  const int m0 = bm << 8, n0 = bn << 8;
  const int t = threadIdx.x, lane = t & 63, wid = t >> 6;
  const int wr = wid >> 2, wcn = wid & 3;
  const int hi = lane >> 4, lo = lane & 15;
  const int srow = lane >> 3, sc8 = lane & 7;
  const int gcs = (sc8 ^ srow) * 8;  // pre-swizzled global column (elements)
  const ushort* Abase = A + (size_t)m0 * K;
  const ushort* Bbase = B + (size_t)n0 * K;
  f32x4 acc[8][4] = {};
  short8 a[4][2], b0[2][2], b1[2][2];

  auto stage = [&](int buf, int mat, int h, int tt) {
    const ushort* G = mat ? Bbase : Abase;
    char* L = (char*)lds[buf] + mat * 32768;
    const size_t kof = (size_t)tt * 64 + gcs;
    #pragma unroll
    for (int j = 0; j < 2; j++) {
      const int rb = h * 128 + wid * 16 + j * 8;
      GLOAD_LDS16(G + (size_t)(rb + srow) * K + kof, (ushort*)(L + rb * 128));
    }
  };
  auto rdA = [&](const char* LA, int MP, short8 af[4][2]) {
    #pragma unroll
    for (int m = 0; m < 4; m++) {
      const int row = MP * 128 + wr * 64 + m * 16 + lo;
      const int sz = (row & 7) << 4;
      #pragma unroll
      for (int kk = 0; kk < 2; kk++)
        af[m][kk] = *(const short8*)(LA + row * 128 + ((kk * 64 + hi * 16) ^ sz));
    }
  };
  auto rdB = [&](const char* LB, int NP, short8 bq[2][2]) {
    #pragma unroll
    for (int n = 0; n < 2; n++) {
      const int row = NP * 128 + wcn * 32 + n * 16 + lo;
      const int sz = (row & 7) << 4;
      #pragma unroll
      for (int kk = 0; kk < 2; kk++)
        bq[n][kk] = *(const short8*)(LB + row * 128 + ((kk * 64 + hi * 16) ^ sz));
    }
  };
  auto mfma16 = [&](int MP, int NP, short8 af[4][2], short8 bq[2][2]) {
    __builtin_amdgcn_s_setprio(1);
    #pragma unroll
    for (int m = 0; m < 4; m++)
      #pragma unroll
      for (int n = 0; n < 2; n++) {
        acc[MP*4+m][NP*2+n] = __builtin_amdgcn_mfma_f32_16x16x32_bf16(af[m][0], bq[n][0], acc[MP*4+m][NP*2+n], 0, 0, 0);
        acc[MP*4+m][NP*2+n] = __builtin_amdgcn_mfma_f32_16x16x32_bf16(af[m][1], bq[n][1], acc[MP*4+m][NP*2+n], 0, 0, 0);
      }
    __builtin_amdgcn_s_setprio(0);
  };

  const int NT = K >> 6, NI = NT >> 1;
  // prologue: tile0 A0,B0,B1,A1 -> buf0; tile1 A0,B0,B1 -> buf1 (A1(v) at ph0)
  stage(0, 0, 0, 0); stage(0, 1, 0, 0); stage(0, 1, 1, 0); stage(0, 0, 1, 0);
  stage(1, 0, 0, 1); stage(1, 1, 0, 1); stage(1, 1, 1, 1);
  VM6; BAR;  // drains buf0's 4 halves; leaves buf1's A0,B0,B1 (6) in flight

  const char* LA0 = (const char*)lds[0]; const char* LB0 = (const char*)lds[0] + 32768;
  const char* LA1 = (const char*)lds[1]; const char* LB1 = (const char*)lds[1] + 32768;

  for (int i = 0; i < NI; ++i) {
    const int u = 2 * i;
    const bool lastI = (i == NI - 1);
    // ph0: rd A0,B0(u); stage A1(v)->buf1
    rdA(LA0, 0, a); rdB(LB0, 0, b0);
    stage(1, 0, 1, u + 1);
    BAR; mfma16(0, 0, a, b0);
    // ph1: rd B1(u)
    rdB(LB0, 1, b1);
    BAR; mfma16(0, 1, a, b1);
    // ph2: rd A1(u); stage A0+B0(u+2)->buf0
    rdA(LA0, 1, a);
    if (!lastI) { stage(0, 0, 0, u + 2); stage(0, 1, 0, u + 2); }
    BAR; mfma16(1, 1, a, b1);
    // ph3: stage B1(u+2); VM6 validates buf1(v)
    if (!lastI) stage(0, 1, 1, u + 2);
    if (lastI) { VM0; } else { VM6; }
    BAR; mfma16(1, 0, a, b0);
    // ph4: rd A0,B0(v) [buf1]; stage A1(u+2)->buf0
    rdA(LA1, 0, a); rdB(LB1, 0, b0);
    if (!lastI) stage(0, 0, 1, u + 2);
    BAR; mfma16(0, 0, a, b0);
    // ph5: rd B1(v)
    rdB(LB1, 1, b1);
    BAR; mfma16(0, 1, a, b1);
    // ph6: rd A1(v); stage A0+B0(u+3)->buf1
    rdA(LA1, 1, a);
    if (!lastI) { stage(1, 0, 0, u + 3); stage(1, 1, 0, u + 3); }
    BAR; mfma16(1, 1, a, b1);
    // ph7: stage B1(u+3); VM6 validates buf0(u+2)
    if (!lastI) { stage(1, 1, 1, u + 3); VM6; }
    BAR; mfma16(1, 0, a, b0);
  }

  #pragma unroll
  for (int mi = 0; mi < 8; mi++) {
    const int grow = m0 + (mi >> 2) * 128 + wr * 64 + (mi & 3) * 16 + hi * 4;
    #pragma unroll
    for (int ni = 0; ni < 4; ni++) {
      const int gcol = n0 + (ni >> 1) * 128 + wcn * 32 + (ni & 1) * 16 + lo;
      const float bv = bias[gcol];
      #pragma unroll
      for (int r = 0; r < 4; r++) {
        const size_t idx = (size_t)(grow + r) * N + gcol;
        float v = acc[mi][ni][r] + bv;
        if constexpr (EPI == 0) ((ushort*)outp)[idx] = f2bf(v);
        else if constexpr (EPI == 1) ((float*)outp)[idx] = res[idx] + v;
        else if constexpr (EPI == 2) ((ushort*)outp)[idx] = f2bf(0.5f * v * (1.f + erff(v * 0.70710678118f)));
        else ((float*)outp)[idx] += v;
      }
    }
  }
}

// ---------------- causal flash attention (verified R5 structure) ----------------
__global__ __launch_bounds__(256) void attn_k(const ushort* __restrict__ qkv, ushort* __restrict__ o) {
  const int qb = 15 - blockIdx.y;
  const int bh = blockIdx.x;
  const int bb = bh >> 4, h = bh & 15;
  const int t = threadIdx.x, lane = t & 63, w = t >> 6;
  const int hi = lane >> 4, lo = lane & 15;
  __shared__ __align__(16) char ldsK[64 * 256];
  __shared__ __align__(16) char ldsV[64 * 256];
  __shared__ __align__(16) char ldsP[4][16 * 128];
  const size_t base = (size_t)bb * 1024 * 6144;
  const int qrow_a = qb * 64 + w * 16 + lo;
  short8 qf[4];
  #pragma unroll
  for (int kk = 0; kk < 4; kk++)
    qf[kk] = *(const short8*)(qkv + base + (size_t)qrow_a * 6144 + h * 128 + kk * 32 + hi * 8);
  float ms[4], ls[4];
  f32x4 oacc[8] = {};
  #pragma unroll
  for (int r = 0; r < 4; r++) { ms[r] = -1e30f; ls[r] = 0.f; }
  const int wave_qmax = qb * 64 + w * 16 + 15;
  const uint vbase = (uint)(size_t)(lds_char*)ldsV + hi * 2048 + lo * 8;
  const int k_r4  = lane >> 4;
  const int v_kv4 = (lane >> 1) & 3;
  const int v_d0  = (lane >> 3) * 16 + (lane & 1) * 8;

  for (int kv0 = 0; kv0 <= qb * 64; kv0 += 64) {
    __syncthreads();
    #pragma unroll
    for (int j = 0; j < 4; j++) {
      const int rb = w * 16 + j * 4;
      const int r  = rb + k_r4;
      const int c16 = (lane & 15) ^ (r & 7);
      GLOAD_LDS16(qkv + base + (size_t)(kv0 + r) * 6144 + 2048 + h * 128 + c16 * 8,
                  ldsK + rb * 256);
    }
    #pragma unroll
    for (int j = 0; j < 4; j++) {
      const int g = w * 4 + j;
      GLOAD_LDS16(qkv + base + (size_t)(kv0 + g * 4 + v_kv4) * 6144 + 4096 + h * 128 + v_d0,
                  ldsV + g * 1024);
    }
    __syncthreads();
    if (kv0 > wave_qmax) continue;
    f32x4 s[4];
    #pragma unroll
    for (int nb = 0; nb < 4; nb++) {
      f32x4 z = {};
      const int krow = nb * 16 + lo;
      #pragma unroll
      for (int kk = 0; kk < 4; kk++) {
        const int cb = kk * 64 + hi * 16;
        short8 kf = *(const short8*)(ldsK + krow * 256 + (cb ^ ((krow & 7) << 4)));
        z = __builtin_amdgcn_mfma_f32_16x16x32_bf16(qf[kk], kf, z, 0, 0, 0);
      }
      s[nb] = z;
    }
    float corr[4];
    #pragma unroll
    for (int r = 0; r < 4; r++) {
      const int qrow = qb * 64 + w * 16 + hi * 4 + r;
      float mx = -1e30f;
      #pragma unroll
      for (int nb = 0; nb < 4; nb++) {
        const int kcol = kv0 + nb * 16 + lo;
        float sv = s[nb][r] * 0.08838834764831845f;
        sv = (kcol <= qrow) ? sv : -1e30f;
        s[nb][r] = sv;
        mx = fmaxf(mx, sv);
      }
      #pragma unroll
      for (int msk = 1; msk < 16; msk <<= 1) mx = fmaxf(mx, __shfl_xor(mx, msk));
      const float mnew = fmaxf(ms[r], mx);
      corr[r] = __expf(ms[r] - mnew);
      ms[r] = mnew;
      float rs = 0.f;
      #pragma unroll
      for (int nb = 0; nb < 4; nb++) {
        const float p = __expf(s[nb][r] - mnew);
        s[nb][r] = p; rs += p;
      }
      #pragma unroll
      for (int msk = 1; msk < 16; msk <<= 1) rs += __shfl_xor(rs, msk);
      ls[r] = ls[r] * corr[r] + rs;
    }
    #pragma unroll
    for (int nf = 0; nf < 8; nf++)
      #pragma unroll
      for (int r = 0; r < 4; r++) oacc[nf][r] *= corr[r];
    #pragma unroll
    for (int r = 0; r < 4; r++) {
      const int prow = hi * 4 + r;
      #pragma unroll
      for (int nb = 0; nb < 4; nb++) {
        const int pcol = nb * 16 + lo;
        *(short*)(ldsP[w] + prow * 128 + ((pcol * 2) ^ ((prow & 7) << 4))) = (short)f2bf(s[nb][r]);
      }
    }
    #pragma unroll
    for (int ks = 0; ks < 2; ks++) {
      short8 pf = *(const short8*)(ldsP[w] + lo * 128 + ((ks * 64 + hi * 16) ^ ((lo & 7) << 4)));
      short4v v0[8], v1[8];
      #pragma unroll
      for (int nf = 0; nf < 8; nf++) {
        const uint a0 = vbase + ks * 8192 + nf * 128;
        asm volatile("ds_read_b64_tr_b16 %0, %1" : "=v"(v0[nf]) : "v"(a0));
        asm volatile("ds_read_b64_tr_b16 %0, %1" : "=v"(v1[nf]) : "v"(a0 + 1024));
      }
      LGKM0_SB;
      #pragma unroll
      for (int nf = 0; nf < 8; nf++) {
        short8 vf = __builtin_shufflevector(v0[nf], v1[nf], 0, 1, 2, 3, 4, 5, 6, 7);
        oacc[nf] = __builtin_amdgcn_mfma_f32_16x16x32_bf16(pf, vf, oacc[nf], 0, 0, 0);
      }
    }
  }
  #pragma unroll
  for (int r = 0; r < 4; r++) {
    const float inv = 1.f / ls[r];
    const int qrow = qb * 64 + w * 16 + hi * 4 + r;
    ushort* orow = o + ((size_t)(bb * 1024 + qrow)) * 2048 + h * 128;
    #pragma unroll
    for (int nf = 0; nf < 8; nf++)
      orow[nf * 16 + lo] = f2bf(oacc[nf][r] * inv);
  }
}

extern "C" void kernel_launch(void* const* d_in, const int* in_sizes, int n_in,
                              void* d_out, int out_size, void* d_ws, size_t ws_size,
                              hipStream_t stream) {
  const float* x     = (const float*)d_in[0];
  const float* ln1w  = (const float*)d_in[1];
  const float* ln1b  = (const float*)d_in[2];
  const float* qkvw  = (const float*)d_in[3];
  const float* qkvb  = (const float*)d_in[4];
  const float* outw  = (const float*)d_in[5];
  const float* outb  = (const float*)d_in[6];
  const float* ln2w  = (const float*)d_in[7];
  const float* ln2b  = (const float*)d_in[8];
  const float* fc1w  = (const float*)d_in[9];
  const float* fc1b  = (const float*)d_in[10];
  const float* fc2w  = (const float*)d_in[11];
  const float* fc2b  = (const float*)d_in[12];
  float* out = (float*)d_out;

  char* ws = (char*)d_ws;
  ushort* qkvw_bf = (ushort*)(ws);               // 3*2048*2048 bf16
  ushort* outw_bf = (ushort*)(ws + 25165824);    // 2048*2048
  ushort* fc1w_bf = (ushort*)(ws + 33554432);    // 8192*2048
  ushort* fc2w_bf = (ushort*)(ws + 67108864);    // 2048*8192
  ushort* bufA    = (ushort*)(ws + 100663296);   // 8192*2048 bf16: xhat1 -> attnout -> xhat2
  ushort* bufR    = (ushort*)(ws + 134217728);   // 8192*8192 bf16 max: qkv -> gelu-h

  cvt_all_k<<<24576, 256, 0, stream>>>(qkvw, qkvw_bf, 1572864,
                                       outw, outw_bf, 524288,
                                       fc1w, fc1w_bf, 2097152,
                                       fc2w, fc2w_bf, 2097152);

  ln_k<<<8192, 256, 0, stream>>>(x, ln1w, ln1b, bufA);
  gemm256_k<0><<<32 * 24, 512, 0, stream>>>(bufA, qkvw_bf, qkvb, nullptr, bufR, 8192, 6144, 2048);
  attn_k<<<dim3(128, 16), 256, 0, stream>>>(bufR, bufA);
  gemm256_k<1><<<32 * 8, 512, 0, stream>>>(bufA, outw_bf, outb, x, out, 8192, 2048, 2048);
  ln_k<<<8192, 256, 0, stream>>>(out, ln2w, ln2b, bufA);
  gemm256_k<2><<<32 * 32, 512, 0, stream>>>(bufA, fc1w_bf, fc1b, nullptr, bufR, 8192, 8192, 2048);
  gemm256_k<3><<<32 * 8, 512, 0, stream>>>(bufR, fc2w_bf, fc2b, nullptr, out, 8192, 2048, 8192);
}